// Round 2
// baseline (584.359 us; speedup 1.0000x reference)
//
#include <hip/hip_runtime.h>

#define DN 128
#define AN 128
#define HN 4
#define FN 128
#define L2N 50
#define NPOS (64*200)
#define KSTR 51   // odd stride: lane-varies-d LDS patterns are conflict-free

__global__ __launch_bounds__(256) void mha_fused(
    const int* __restrict__ queries,
    const int* __restrict__ keys,
    const float* __restrict__ E,
    const float* __restrict__ Wq,
    const float* __restrict__ bq,
    const float* __restrict__ Wk,
    const float* __restrict__ bk,
    const float* __restrict__ Wv,
    const float* __restrict__ bv,
    const float* __restrict__ Wf,
    const float* __restrict__ bfb,
    float* __restrict__ out)
{
    __shared__ float kT[DN][KSTR];                 // k_emb transposed [d][r]
    __shared__ __align__(16) float qe[DN];         // q_emb
    __shared__ float Qs[AN];                       // Q projection
    __shared__ __align__(16) float us[HN][DN];     // u_h = Wk_h^T Q_h
    __shared__ float offs[HN];                     // bk_h . Q_h
    __shared__ float rsum[L2N];                    // row sums for mask
    __shared__ __align__(16) float attn[HN][52];   // softmax weights (52 for f4 align)
    __shared__ __align__(16) float pvs[HN][DN];    // pv_h = attn_h^T k_emb
    __shared__ __align__(16) float outs[AN];       // attn out + residual

    const int pos  = blockIdx.x;
    const int tid  = threadIdx.x;
    const int lane = tid & 63;
    const int wave = tid >> 6;

    // ---- Stage 1: gather q_emb + k_emb (transposed) into LDS ----
    const int qidx = queries[pos];
    if (tid < 64) {
        float2 v = *(const float2*)(E + (size_t)qidx * DN + tid * 2);
        qe[tid*2]   = v.x;
        qe[tid*2+1] = v.y;
    }
    const int kb = pos * L2N;
    for (int i = tid; i < L2N * 64; i += 256) {
        int r  = i >> 6;          // key row 0..49
        int c  = i & 63;          // float2 index within row
        int kidx = keys[kb + r];
        float2 v = *(const float2*)(E + (size_t)kidx * DN + c * 2);
        kT[c*2][r]   = v.x;
        kT[c*2+1][r] = v.y;
    }
    __syncthreads();

    // ---- Stage 2: Q = q_emb@Wq + bq (waves 0,1) ; row sums for mask (wave 2) ----
    if (wave < 2) {
        int a = wave * 64 + lane;           // output column, coalesced weight reads
        float acc = bq[a];
        for (int d = 0; d < DN; d += 4) {
            float4 q4 = *(const float4*)&qe[d];
            acc += q4.x * Wq[(d    ) * AN + a];
            acc += q4.y * Wq[(d + 1) * AN + a];
            acc += q4.z * Wq[(d + 2) * AN + a];
            acc += q4.w * Wq[(d + 3) * AN + a];
        }
        Qs[a] = acc;
    } else if (wave == 2 && lane < L2N) {
        float s = 0.f;
        for (int d = 0; d < DN; ++d) s += kT[d][lane];
        rsum[lane] = s;
    }
    __syncthreads();

    // ---- Stage 3: u[h][d] = sum_{a in head h} Wk[d][a]*Q[a]  (coalesced + shfl tree)
    {
        int a  = ((wave & 1) << 6) + lane;  // waves 0,1 vs 2,3 split d-range
        int h  = a >> 5;
        int d0 = (wave >> 1) << 6;
        float qa = Qs[a];
        for (int d = d0; d < d0 + 64; ++d) {
            float p = Wk[d * AN + a] * qa;
            p += __shfl_xor(p, 16);
            p += __shfl_xor(p, 8);
            p += __shfl_xor(p, 4);
            p += __shfl_xor(p, 2);
            p += __shfl_xor(p, 1);
            if ((lane & 31) == 0) us[h][d] = p;
        }
        if (wave < 2) {                     // offs[h] = bk_h . Q_h
            float p = bk[a] * qa;
            p += __shfl_xor(p, 16);
            p += __shfl_xor(p, 8);
            p += __shfl_xor(p, 4);
            p += __shfl_xor(p, 2);
            p += __shfl_xor(p, 1);
            if ((lane & 31) == 0) offs[h] = p;
        }
    }
    __syncthreads();

    // ---- Stage 4: scores[h][r] = (kT[:,r].us[h] + offs[h])/sqrt(32), mask, softmax
    {
        const int h = wave;                 // one head per wave
        const int r = lane;
        float sc;
        if (r < L2N) {
            float acc = 0.f;
            for (int d = 0; d < DN; d += 4) {
                float4 u4 = *(const float4*)&us[h][d];
                acc += kT[d    ][r] * u4.x;
                acc += kT[d + 1][r] * u4.y;
                acc += kT[d + 2][r] * u4.z;
                acc += kT[d + 3][r] * u4.w;
            }
            sc = (acc + offs[h]) * 0.17677669529663687f;  // 1/sqrt(32)
            if (rsum[r] == 0.0f) sc = -4294967295.0f;     // NEG mask
        } else {
            sc = -__builtin_inff();
        }
        float mx = sc;
        mx = fmaxf(mx, __shfl_xor(mx, 32));
        mx = fmaxf(mx, __shfl_xor(mx, 16));
        mx = fmaxf(mx, __shfl_xor(mx, 8));
        mx = fmaxf(mx, __shfl_xor(mx, 4));
        mx = fmaxf(mx, __shfl_xor(mx, 2));
        mx = fmaxf(mx, __shfl_xor(mx, 1));
        float e = (r < L2N) ? __expf(sc - mx) : 0.f;
        float s = e;
        s += __shfl_xor(s, 32);
        s += __shfl_xor(s, 16);
        s += __shfl_xor(s, 8);
        s += __shfl_xor(s, 4);
        s += __shfl_xor(s, 2);
        s += __shfl_xor(s, 1);
        if (r < L2N) attn[h][r] = e / s;
    }
    __syncthreads();

    // ---- Stage 5: pv[h][d] = sum_r attn[h][r] * kT[d][r] ----
    if (tid < 128) {
        const int d = tid;
        float a0 = 0.f, a1 = 0.f, a2 = 0.f, a3 = 0.f;
        for (int rc = 0; rc < 48; rc += 4) {
            float4 w0 = *(const float4*)&attn[0][rc];
            float4 w1 = *(const float4*)&attn[1][rc];
            float4 w2 = *(const float4*)&attn[2][rc];
            float4 w3 = *(const float4*)&attn[3][rc];
            float k0 = kT[d][rc], k1 = kT[d][rc+1], k2 = kT[d][rc+2], k3 = kT[d][rc+3];
            a0 += w0.x*k0 + w0.y*k1 + w0.z*k2 + w0.w*k3;
            a1 += w1.x*k0 + w1.y*k1 + w1.z*k2 + w1.w*k3;
            a2 += w2.x*k0 + w2.y*k1 + w2.z*k2 + w2.w*k3;
            a3 += w3.x*k0 + w3.y*k1 + w3.z*k2 + w3.w*k3;
        }
        for (int r = 48; r < L2N; ++r) {
            float kv = kT[d][r];
            a0 += attn[0][r] * kv;
            a1 += attn[1][r] * kv;
            a2 += attn[2][r] * kv;
            a3 += attn[3][r] * kv;
        }
        pvs[0][d] = a0; pvs[1][d] = a1; pvs[2][d] = a2; pvs[3][d] = a3;
    }
    __syncthreads();

    // ---- Stage 6: out[a] = pv_{h(a)} . Wv[:,a] + bv[a] + q_emb[a] ----
    if (tid < 128) {
        const int a = tid;
        const int h = a >> 5;
        float acc = bv[a];
        for (int d = 0; d < DN; d += 4) {
            float4 p4 = *(const float4*)&pvs[h][d];
            acc += p4.x * Wv[(d    ) * AN + a];
            acc += p4.y * Wv[(d + 1) * AN + a];
            acc += p4.z * Wv[(d + 2) * AN + a];
            acc += p4.w * Wv[(d + 3) * AN + a];
        }
        outs[a] = acc + qe[a];
    }
    __syncthreads();

    // ---- Stage 7: final[f] = outs . Wf[:,f] + bf[f] ----
    if (tid < 128) {
        const int f = tid;
        float acc = bfb[f];
        for (int a = 0; a < AN; a += 4) {
            float4 o4 = *(const float4*)&outs[a];
            acc += o4.x * Wf[(a    ) * FN + f];
            acc += o4.y * Wf[(a + 1) * FN + f];
            acc += o4.z * Wf[(a + 2) * FN + f];
            acc += o4.w * Wf[(a + 3) * FN + f];
        }
        out[(size_t)pos * FN + f] = acc;
    }
}

extern "C" void kernel_launch(void* const* d_in, const int* in_sizes, int n_in,
                              void* d_out, int out_size, void* d_ws, size_t ws_size,
                              hipStream_t stream) {
    const int* queries = (const int*)d_in[0];
    const int* keys    = (const int*)d_in[1];
    const float* E   = (const float*)d_in[2];
    const float* Wq  = (const float*)d_in[3];
    const float* bq  = (const float*)d_in[4];
    const float* Wk  = (const float*)d_in[5];
    const float* bk  = (const float*)d_in[6];
    const float* Wv  = (const float*)d_in[7];
    const float* bv  = (const float*)d_in[8];
    const float* Wf  = (const float*)d_in[9];
    const float* bfb = (const float*)d_in[10];
    float* o = (float*)d_out;

    hipLaunchKernelGGL(mha_fused, dim3(NPOS), dim3(256), 0, stream,
                       queries, keys, E, Wq, bq, Wk, bk, Wv, bv, Wf, bfb, o);
}

// Round 4
// 315.384 us; speedup vs baseline: 1.8528x; 1.8528x over previous
//
#include <hip/hip_runtime.h>
#include <stdint.h>

#define DN 128
#define AN 128
#define HN 4
#define FN 128
#define L2N 50
#define NPOS (64*200)
#define PPB 4
#define NBLK (NPOS/PPB)   // 3200
#define NEGC (-4294967295.0f)

// ws layout (float offsets)
#define OFF_MT   0        // [128][512] f32  : MT[dd][h*128+d]
#define OFF_GT2  65536    // [256][128] u32  : GT2[j][f] = half2(GT[2j][f], GT[2j+1][f])
#define OFF_C    98304    // [512] f32       : Wk_h^T bq
#define OFF_WB   98816    // [128][4] f32    : wb[dd][h] = Sum_a Wq[dd][a] bk[a]
#define OFF_ZB   99328    // [4] f32         : bq_h . bk_h
#define OFF_B0   99332    // [128] f32       : bv@Wf + bf
#define WS_TOT   99460

typedef __fp16 half2v __attribute__((ext_vector_type(2)));

__device__ __forceinline__ float dot2(uint32_t a, uint32_t b, float c) {
#if __has_builtin(__builtin_amdgcn_fdot2)
    union { uint32_t u; half2v h; } ca, cb; ca.u = a; cb.u = b;
    return __builtin_amdgcn_fdot2(ca.h, cb.h, c, false);
#else
    union { uint32_t u; _Float16 h[2]; } ca, cb; ca.u = a; cb.u = b;
    return c + (float)ca.h[0]*(float)cb.h[0] + (float)ca.h[1]*(float)cb.h[1];
#endif
}

__device__ __forceinline__ uint32_t packh2(float x, float y) {
#if __has_builtin(__builtin_amdgcn_cvt_pkrtz)
    union { half2v h; uint32_t u; } c; c.h = __builtin_amdgcn_cvt_pkrtz(x, y);
    return c.u;
#else
    union { _Float16 h[2]; uint32_t u; } c; c.h[0] = (_Float16)x; c.h[1] = (_Float16)y;
    return c.u;
#endif
}

__device__ __forceinline__ float lo16f(uint32_t u) {
    union { uint32_t u; _Float16 h[2]; } c; c.u = u; return (float)c.h[0];
}
__device__ __forceinline__ float hi16f(uint32_t u) {
    union { uint32_t u; _Float16 h[2]; } c; c.u = u; return (float)c.h[1];
}

// ---------------- K0: fold weights ----------------
__global__ __launch_bounds__(256) void precomp(
    const float* __restrict__ Wq, const float* __restrict__ bq,
    const float* __restrict__ Wk, const float* __restrict__ bk,
    const float* __restrict__ Wv, const float* __restrict__ bv,
    const float* __restrict__ Wf, const float* __restrict__ bfb,
    float* __restrict__ ws)
{
    int idx = blockIdx.x*256 + threadIdx.x;
    if (idx < 65536) {                       // MT[dd][out]
        int dd = idx >> 9, outc = idx & 511;
        int h = outc >> 7, d = outc & 127;
        const float* wq = Wq + dd*AN + h*32;
        const float* wk = Wk + d*AN + h*32;
        float s = 0.f;
        for (int j = 0; j < 32; ++j) s += wq[j]*wk[j];
        ws[OFF_MT + idx] = s;
    } else if (idx < 65536+32768) {          // GT2[j][f]
        int i2 = idx - 65536;
        int j = i2 >> 7, f = i2 & 127;
        int hd = 2*j; int h = hd >> 7, d = hd & 127;
        const float* wv0 = Wv + d*AN + h*32;
        const float* wv1 = Wv + (d+1)*AN + h*32;
        float s0 = 0.f, s1 = 0.f;
        for (int a = 0; a < 32; ++a) {
            float wf = Wf[(h*32+a)*FN + f];
            s0 += wv0[a]*wf; s1 += wv1[a]*wf;
        }
        ((uint32_t*)ws)[OFF_GT2 + i2] = packh2(s0, s1);
    } else if (idx < 98816) {                // C
        int outc = idx - 98304; int h = outc >> 7, d = outc & 127;
        float s = 0.f;
        for (int j = 0; j < 32; ++j) s += Wk[d*AN + h*32 + j]*bq[h*32 + j];
        ws[OFF_C + outc] = s;
    } else if (idx < 99328) {                // WB
        int i = idx - 98816; int dd = i >> 2, h = i & 3;
        float s = 0.f;
        for (int j = 0; j < 32; ++j) s += Wq[dd*AN + h*32 + j]*bk[h*32 + j];
        ws[OFF_WB + i] = s;
    } else if (idx < 99332) {                // ZB
        int h = idx - 99328; float s = 0.f;
        for (int j = 0; j < 32; ++j) s += bq[h*32 + j]*bk[h*32 + j];
        ws[OFF_ZB + h] = s;
    } else if (idx < WS_TOT) {               // B0
        int f = idx - 99332; float s = bfb[f];
        for (int a = 0; a < AN; ++a) s += bv[a]*Wf[a*FN + f];
        ws[OFF_B0 + f] = s;
    }
}

// ---------------- main fused kernel ----------------
__global__ __launch_bounds__(256, 2) void mha_main(
    const int* __restrict__ queries, const int* __restrict__ keys,
    const float* __restrict__ E, const float* __restrict__ Wf,
    const float* __restrict__ ws, float* __restrict__ out)
{
    __shared__ __align__(16) uint32_t kT2f[PPB][64][51];   // half2(k[2dp],k[2dp+1]) by [pos][dp][r]
    __shared__ __align__(16) uint32_t usT2[PPB][HN][64];   // u as half2 pairs
    __shared__ __align__(16) uint32_t attnP[PPB][L2N][2];  // half2(w0,w1),half2(w2,w3)
    __shared__ __align__(16) uint32_t pv2[PPB][256];       // pv as half2 pairs, flat hd
    __shared__ __align__(16) float offs_s[PPB][4];
    __shared__ float fsum[PPB][FN];
    __shared__ int idx_s[PPB][L2N];

    const int t   = threadIdx.x;
    const int wv  = t >> 6;
    const int ln  = t & 63;
    const int pos0 = blockIdx.x * PPB;

    const float*    MT  = ws + OFF_MT;
    const uint32_t* GT2 = (const uint32_t*)ws + OFF_GT2;
    const float*    Cv  = ws + OFF_C;
    const float*    WB  = ws + OFF_WB;
    const float*    ZB  = ws + OFF_ZB;
    const float*    B0  = ws + OFF_B0;

    int qidx[PPB];
    #pragma unroll
    for (int p = 0; p < PPB; ++p) qidx[p] = queries[pos0 + p];   // uniform -> s_load

    // ---- Stage A: key indices ----
    if (t < PPB*L2N) idx_s[t/L2N][t%L2N] = keys[pos0*L2N + t];
    __syncthreads();

    // ---- Stage B: gather k rows -> f16-packed LDS (2-deep pipelined) ----
    {
        float2 nv;
        {
            int row = wv; int p = row/50, rr = row%50;
            nv = *(const float2*)(E + (size_t)idx_s[p][rr]*DN + 2*ln);
        }
        for (int it = 0; it < 50; ++it) {
            float2 cv = nv;
            int row = it*4 + wv;
            if (it < 49) {
                int row2 = row + 4; int p2 = row2/50, rr2 = row2%50;
                nv = *(const float2*)(E + (size_t)idx_s[p2][rr2]*DN + 2*ln);
            }
            int p = row/50, rr = row%50;
            kT2f[p][ln][rr] = packh2(cv.x, cv.y);
        }
    }

    // ---- Stage C: u = MT . q_emb + c  (scalar-broadcast q, coalesced MT) ----
    {
        float ua[PPB], ub[PPB];
        float2 cv = *(const float2*)(Cv + 2*t);
        #pragma unroll
        for (int p = 0; p < PPB; ++p) { ua[p] = cv.x; ub[p] = cv.y; }
        const float* mrow = MT + 2*t;
        #pragma unroll 8
        for (int dd = 0; dd < DN; ++dd) {
            float2 m = *(const float2*)(mrow + (size_t)dd*512);
            #pragma unroll
            for (int p = 0; p < PPB; ++p) {
                float q = E[(size_t)qidx[p]*DN + dd];   // uniform -> SGPR broadcast
                ua[p] += q*m.x; ub[p] += q*m.y;
            }
        }
        int h = t >> 6, dp = t & 63;
        #pragma unroll
        for (int p = 0; p < PPB; ++p) usT2[p][h][dp] = packh2(ua[p], ub[p]);
    }
    // score offsets: offs[p][h] = q_emb . wb[:,h] + zb[h]
    if (t < 16) {
        int p = t >> 2, h = t & 3;
        float a = ZB[h];
        const float* eq = E + (size_t)qidx[p]*DN;
        for (int dd = 0; dd < DN; ++dd) a += eq[dd] * WB[dd*4 + h];
        offs_s[p][h] = a;
    }
    __syncthreads();

    // ---- Stage D: scores + mask + softmax (wave = position) ----
    {
        const int p = wv;
        const int r = ln;
        const int rc = (r < L2N) ? r : 0;
        float acc0=0.f, acc1=0.f, acc2=0.f, acc3=0.f, ksum=0.f;
        const uint32_t ONE2 = 0x3C003C00u;   // half2(1,1)
        #pragma unroll 4
        for (int dp = 0; dp < 64; dp += 4) {
            uint4 u0 = *(const uint4*)&usT2[p][0][dp];
            uint4 u1 = *(const uint4*)&usT2[p][1][dp];
            uint4 u2 = *(const uint4*)&usT2[p][2][dp];
            uint4 u3 = *(const uint4*)&usT2[p][3][dp];
            uint32_t k0 = kT2f[p][dp+0][rc];
            uint32_t k1 = kT2f[p][dp+1][rc];
            uint32_t k2 = kT2f[p][dp+2][rc];
            uint32_t k3 = kT2f[p][dp+3][rc];
            acc0 = dot2(k0,u0.x,acc0); acc0 = dot2(k1,u0.y,acc0);
            acc0 = dot2(k2,u0.z,acc0); acc0 = dot2(k3,u0.w,acc0);
            acc1 = dot2(k0,u1.x,acc1); acc1 = dot2(k1,u1.y,acc1);
            acc1 = dot2(k2,u1.z,acc1); acc1 = dot2(k3,u1.w,acc1);
            acc2 = dot2(k0,u2.x,acc2); acc2 = dot2(k1,u2.y,acc2);
            acc2 = dot2(k2,u2.z,acc2); acc2 = dot2(k3,u2.w,acc2);
            acc3 = dot2(k0,u3.x,acc3); acc3 = dot2(k1,u3.y,acc3);
            acc3 = dot2(k2,u3.z,acc3); acc3 = dot2(k3,u3.w,acc3);
            ksum = dot2(k0,ONE2,ksum); ksum = dot2(k1,ONE2,ksum);
            ksum = dot2(k2,ONE2,ksum); ksum = dot2(k3,ONE2,ksum);
        }
        float4 offv = *(const float4*)&offs_s[p][0];
        float sc[4];
        sc[0] = (acc0 + offv.x) * 0.17677669529663687f;
        sc[1] = (acc1 + offv.y) * 0.17677669529663687f;
        sc[2] = (acc2 + offv.z) * 0.17677669529663687f;
        sc[3] = (acc3 + offv.w) * 0.17677669529663687f;
        if (ksum == 0.0f) { sc[0]=NEGC; sc[1]=NEGC; sc[2]=NEGC; sc[3]=NEGC; }
        if (r >= L2N) { sc[0]=-__builtin_inff(); sc[1]=-__builtin_inff();
                        sc[2]=-__builtin_inff(); sc[3]=-__builtin_inff(); }
        float w[4];
        #pragma unroll
        for (int h = 0; h < 4; ++h) {
            float m = sc[h];
            m = fmaxf(m, __shfl_xor(m,32)); m = fmaxf(m, __shfl_xor(m,16));
            m = fmaxf(m, __shfl_xor(m, 8)); m = fmaxf(m, __shfl_xor(m, 4));
            m = fmaxf(m, __shfl_xor(m, 2)); m = fmaxf(m, __shfl_xor(m, 1));
            float e = (r < L2N) ? __expf(sc[h] - m) : 0.f;
            float s = e;
            s += __shfl_xor(s,32); s += __shfl_xor(s,16); s += __shfl_xor(s,8);
            s += __shfl_xor(s, 4); s += __shfl_xor(s, 2); s += __shfl_xor(s,1);
            w[h] = e / s;
        }
        if (r < L2N) {
            attnP[p][r][0] = packh2(w[0], w[1]);
            attnP[p][r][1] = packh2(w[2], w[3]);
        }
    }
    __syncthreads();

    // ---- Stage E: pv_h = attn_h^T k  (wave = position, lane = d-pair) ----
    {
        const int p = wv; const int dp = ln;
        float pa0=0,pb0=0,pa1=0,pb1=0,pa2=0,pb2=0,pa3=0,pb3=0;
        #pragma unroll 2
        for (int r = 0; r < L2N; ++r) {
            uint2 aw = *(const uint2*)&attnP[p][r][0];    // broadcast
            float w0 = lo16f(aw.x), w1 = hi16f(aw.x);
            float w2 = lo16f(aw.y), w3 = hi16f(aw.y);
            uint32_t kp = kT2f[p][dp][r];
            float kx = lo16f(kp), ky = hi16f(kp);
            pa0 += w0*kx; pb0 += w0*ky;
            pa1 += w1*kx; pb1 += w1*ky;
            pa2 += w2*kx; pb2 += w2*ky;
            pa3 += w3*kx; pb3 += w3*ky;
        }
        pv2[p][0*64+dp] = packh2(pa0,pb0);
        pv2[p][1*64+dp] = packh2(pa1,pb1);
        pv2[p][2*64+dp] = packh2(pa2,pb2);
        pv2[p][3*64+dp] = packh2(pa3,pb3);
    }
    __syncthreads();

    // ---- Stage F: final[f] = pv.GT + q_emb.Wf + bias0, split over 2 halves ----
    {
        const int f = t & 127;
        const int half = t >> 7;
        float acc[PPB] = {0.f,0.f,0.f,0.f};
        const int j0 = half*128;
        #pragma unroll 4
        for (int jc = j0; jc < j0+128; jc += 4) {
            uint32_t g0 = GT2[(jc+0)*FN + f];
            uint32_t g1 = GT2[(jc+1)*FN + f];
            uint32_t g2 = GT2[(jc+2)*FN + f];
            uint32_t g3 = GT2[(jc+3)*FN + f];
            #pragma unroll
            for (int p = 0; p < PPB; ++p) {
                uint4 pvv = *(const uint4*)&pv2[p][jc];   // broadcast
                acc[p] = dot2(pvv.x,g0,acc[p]);
                acc[p] = dot2(pvv.y,g1,acc[p]);
                acc[p] = dot2(pvv.z,g2,acc[p]);
                acc[p] = dot2(pvv.w,g3,acc[p]);
            }
        }
        if (half == 1) {   // add residual q_emb@Wf + bias0
            float b0 = B0[f];
            #pragma unroll
            for (int p = 0; p < PPB; ++p) acc[p] += b0;
            #pragma unroll 8
            for (int dd = 0; dd < DN; ++dd) {
                float wf = Wf[dd*FN + f];
                #pragma unroll
                for (int p = 0; p < PPB; ++p)
                    acc[p] += E[(size_t)qidx[p]*DN + dd] * wf;   // SGPR broadcast
            }
            #pragma unroll
            for (int p = 0; p < PPB; ++p) fsum[p][f] = acc[p];
        }
        __syncthreads();
        if (half == 0) {
            #pragma unroll
            for (int p = 0; p < PPB; ++p)
                out[(size_t)(pos0+p)*FN + f] = acc[p] + fsum[p][f];
        }
    }
}

extern "C" void kernel_launch(void* const* d_in, const int* in_sizes, int n_in,
                              void* d_out, int out_size, void* d_ws, size_t ws_size,
                              hipStream_t stream) {
    const int* queries = (const int*)d_in[0];
    const int* keys    = (const int*)d_in[1];
    const float* E   = (const float*)d_in[2];
    const float* Wq  = (const float*)d_in[3];
    const float* bq  = (const float*)d_in[4];
    const float* Wk  = (const float*)d_in[5];
    const float* bk  = (const float*)d_in[6];
    const float* Wv  = (const float*)d_in[7];
    const float* bv  = (const float*)d_in[8];
    const float* Wf  = (const float*)d_in[9];
    const float* bfb = (const float*)d_in[10];
    float* ws = (float*)d_ws;
    float* o  = (float*)d_out;

    hipLaunchKernelGGL(precomp, dim3((WS_TOT + 255)/256), dim3(256), 0, stream,
                       Wq, bq, Wk, bk, Wv, bv, Wf, bfb, ws);
    hipLaunchKernelGGL(mha_main, dim3(NBLK), dim3(256), 0, stream,
                       queries, keys, E, Wf, ws, o);
}

// Round 5
// 302.129 us; speedup vs baseline: 1.9341x; 1.0439x over previous
//
#include <hip/hip_runtime.h>
#include <stdint.h>

#define DN 128
#define AN 128
#define HN 4
#define FN 128
#define L2N 50
#define NPOS (64*200)
#define NEGC (-4294967295.0f)

// ws layout (float/u32 offsets, 4B units)
#define OFF_MTW2 0         // u32 [64 dd2][640]  : cols 0..511 = MT pairs(dd), 512..639 = Wf pairs(dd)
#define OFF_GT2  40960     // u32 [256 j][128 f] : half2(GT[2j][f],GT[2j+1][f]), j over flat hd
#define OFF_CB   73728     // f32 [640]          : 0..511 = Wk_h^T bq ; 512..639 = bv@Wf+bf
#define OFF_U    74368     // u32 [12800][256]   : u as half2 pairs along outc
#define OFF_R    3351168   // f32 [12800][128]   : qe@Wf + B0
#define OFF_PV   4989568   // u32 [12800][256]   : pv as half2 pairs along flat hd

typedef __fp16 half2v __attribute__((ext_vector_type(2)));

__device__ __forceinline__ float dot2(uint32_t a, uint32_t b, float c) {
#if __has_builtin(__builtin_amdgcn_fdot2)
    union { uint32_t u; half2v h; } ca, cb; ca.u = a; cb.u = b;
    return __builtin_amdgcn_fdot2(ca.h, cb.h, c, false);
#else
    union { uint32_t u; _Float16 h[2]; } ca, cb; ca.u = a; cb.u = b;
    return c + (float)ca.h[0]*(float)cb.h[0] + (float)ca.h[1]*(float)cb.h[1];
#endif
}
// RTNE f16 pack (plain casts -> v_cvt_f16_f32, round-nearest-even)
__device__ __forceinline__ uint32_t packh2(float x, float y) {
    union { _Float16 h[2]; uint32_t u; } c; c.h[0] = (_Float16)x; c.h[1] = (_Float16)y;
    return c.u;
}
__device__ __forceinline__ float lo16f(uint32_t u) {
    union { uint32_t u; _Float16 h[2]; } c; c.u = u; return (float)c.h[0];
}
__device__ __forceinline__ float hi16f(uint32_t u) {
    union { uint32_t u; _Float16 h[2]; } c; c.u = u; return (float)c.h[1];
}

// ================= K0: fold weights (9 tiled blocks) =================
__global__ __launch_bounds__(256) void k0_pre(
    const float* __restrict__ Wq, const float* __restrict__ bq,
    const float* __restrict__ Wk, const float* __restrict__ bk,
    const float* __restrict__ Wv, const float* __restrict__ bv,
    const float* __restrict__ Wf, const float* __restrict__ bfb,
    float* __restrict__ ws)
{
    uint32_t* MTW2 = (uint32_t*)ws + OFF_MTW2;
    uint32_t* GT2w = (uint32_t*)ws + OFF_GT2;
    float*    CB   = ws + OFF_CB;
    const int b = blockIdx.x, t = threadIdx.x;

    if (b < 4) {                    // MT_h = Wq_h @ Wk_h^T  (+ C_h)
        __shared__ float AqL[128][33];
        __shared__ float AkL[128][33];
        const int h = b;
        for (int i = t; i < 4096; i += 256) {
            int dd = i >> 5, j = i & 31;
            AqL[dd][j] = Wq[dd*AN + h*32 + j];
            AkL[dd][j] = Wk[dd*AN + h*32 + j];
        }
        __syncthreads();
        const int tdd = t >> 4, td = t & 15;
        float acc[8][8];
        #pragma unroll
        for (int i = 0; i < 8; ++i)
            #pragma unroll
            for (int k = 0; k < 8; ++k) acc[i][k] = 0.f;
        for (int j = 0; j < 32; ++j) {
            float aq[8], ak[8];
            #pragma unroll
            for (int i = 0; i < 8; ++i) aq[i] = AqL[tdd*8+i][j];
            #pragma unroll
            for (int k = 0; k < 8; ++k) ak[k] = AkL[td*8+k][j];
            #pragma unroll
            for (int i = 0; i < 8; ++i)
                #pragma unroll
                for (int k = 0; k < 8; ++k) acc[i][k] += aq[i]*ak[k];
        }
        #pragma unroll
        for (int i2 = 0; i2 < 4; ++i2)
            #pragma unroll
            for (int k = 0; k < 8; ++k)
                MTW2[(tdd*4+i2)*640 + h*128 + td*8 + k] = packh2(acc[2*i2][k], acc[2*i2+1][k]);
        if (t < 128) {               // C[h*128+d] = Wk_h[d,:] . bq_h
            float s = 0.f;
            for (int j = 0; j < 32; ++j) s += AkL[t][j]*bq[h*32+j];
            CB[h*128 + t] = s;
        }
    } else if (b < 8) {             // GT_h = Wv_h @ Wf_h
        __shared__ float VvL[128][33];
        __shared__ float WfL[32][129];
        const int h = b - 4;
        for (int i = t; i < 4096; i += 256) {
            int d = i >> 5, a = i & 31;
            VvL[d][a] = Wv[d*AN + h*32 + a];
        }
        for (int i = t; i < 4096; i += 256) {
            int a = i >> 7, f = i & 127;
            WfL[a][f] = Wf[(h*32+a)*FN + f];
        }
        __syncthreads();
        const int td = t >> 4, tf = t & 15;
        float acc[8][8];
        #pragma unroll
        for (int i = 0; i < 8; ++i)
            #pragma unroll
            for (int k = 0; k < 8; ++k) acc[i][k] = 0.f;
        for (int a = 0; a < 32; ++a) {
            float av[8], wf8[8];
            #pragma unroll
            for (int i = 0; i < 8; ++i) av[i] = VvL[td*8+i][a];
            #pragma unroll
            for (int k = 0; k < 8; ++k) wf8[k] = WfL[a][tf*8+k];
            #pragma unroll
            for (int i = 0; i < 8; ++i)
                #pragma unroll
                for (int k = 0; k < 8; ++k) acc[i][k] += av[i]*wf8[k];
        }
        #pragma unroll
        for (int i2 = 0; i2 < 4; ++i2)
            #pragma unroll
            for (int k = 0; k < 8; ++k)
                GT2w[(h*64 + td*4 + i2)*128 + tf*8 + k] = packh2(acc[2*i2][k], acc[2*i2+1][k]);
    } else {                        // b==8: Wf pairs -> MTW2 cols 512.. ; B0
        for (int i = t; i < 64*128; i += 256) {
            int dd2 = i >> 7, f = i & 127;
            MTW2[dd2*640 + 512 + f] = packh2(Wf[(2*dd2)*FN + f], Wf[(2*dd2+1)*FN + f]);
        }
        if (t < 128) {
            float s = bfb[t];
            for (int a = 0; a < AN; ++a) s += bv[a]*Wf[a*FN + t];
            CB[512 + t] = s;
        }
    }
}

// ================= K1: U = qe@MT + C ; R = qe@Wf + B0 =================
__global__ __launch_bounds__(256, 1) void k1_proj(
    const int* __restrict__ queries, const float* __restrict__ E,
    float* __restrict__ ws)
{
    const uint32_t* MTW2 = (const uint32_t*)ws + OFF_MTW2;
    const float*    CB   = ws + OFF_CB;
    uint32_t* U = (uint32_t*)ws + OFF_U;
    float*    R = ws + OFF_R;

    const int t = threadIdx.x, wv = t >> 6, ln = t & 63;
    const int pg = ln >> 4, og = ln & 15;
    const int posb = blockIdx.x*64 + wv*16 + pg*4;

    const float* eq[4];
    #pragma unroll
    for (int p = 0; p < 4; ++p)
        eq[p] = E + (size_t)queries[posb + p] * DN;

    #pragma unroll 1
    for (int pass = 0; pass < 5; ++pass) {
        const int outc0 = pass*128 + og*8;
        float acc[4][8];
        float4 b0 = *(const float4*)(CB + outc0);
        float4 b1 = *(const float4*)(CB + outc0 + 4);
        #pragma unroll
        for (int p = 0; p < 4; ++p) {
            acc[p][0]=b0.x; acc[p][1]=b0.y; acc[p][2]=b0.z; acc[p][3]=b0.w;
            acc[p][4]=b1.x; acc[p][5]=b1.y; acc[p][6]=b1.z; acc[p][7]=b1.w;
        }
        #pragma unroll 4
        for (int dd2 = 0; dd2 < 64; ++dd2) {
            uint4 m0 = *(const uint4*)(MTW2 + dd2*640 + outc0);
            uint4 m1 = *(const uint4*)(MTW2 + dd2*640 + outc0 + 4);
            #pragma unroll
            for (int p = 0; p < 4; ++p) {
                float2 q2 = *(const float2*)(eq[p] + 2*dd2);
                uint32_t qp = packh2(q2.x, q2.y);
                acc[p][0] = dot2(qp, m0.x, acc[p][0]);
                acc[p][1] = dot2(qp, m0.y, acc[p][1]);
                acc[p][2] = dot2(qp, m0.z, acc[p][2]);
                acc[p][3] = dot2(qp, m0.w, acc[p][3]);
                acc[p][4] = dot2(qp, m1.x, acc[p][4]);
                acc[p][5] = dot2(qp, m1.y, acc[p][5]);
                acc[p][6] = dot2(qp, m1.z, acc[p][6]);
                acc[p][7] = dot2(qp, m1.w, acc[p][7]);
            }
        }
        if (pass < 4) {             // U: pack pairs along outc
            #pragma unroll
            for (int p = 0; p < 4; ++p) {
                uint4 up;
                up.x = packh2(acc[p][0], acc[p][1]);
                up.y = packh2(acc[p][2], acc[p][3]);
                up.z = packh2(acc[p][4], acc[p][5]);
                up.w = packh2(acc[p][6], acc[p][7]);
                *(uint4*)(U + (size_t)(posb+p)*256 + pass*64 + og*4) = up;
            }
        } else {                    // R: f32
            const int f = og*8;
            #pragma unroll
            for (int p = 0; p < 4; ++p) {
                float4 ra = {acc[p][0], acc[p][1], acc[p][2], acc[p][3]};
                float4 rb = {acc[p][4], acc[p][5], acc[p][6], acc[p][7]};
                *(float4*)(R + (size_t)(posb+p)*128 + f)     = ra;
                *(float4*)(R + (size_t)(posb+p)*128 + f + 4) = rb;
            }
        }
    }
}

// ================= K2: attention core (PPB=2) =================
__global__ __launch_bounds__(256, 5) void k2_attn(
    const int* __restrict__ keys, const float* __restrict__ E,
    const float* __restrict__ ws, float* __restrict__ wsm)
{
    __shared__ __align__(16) uint32_t kT2f[2][64][51];  // half2(k[2dp],k[2dp+1]) [pos][dp][r]
    __shared__ __align__(16) uint32_t U_s[2][HN][64];   // u pairs
    __shared__ uint32_t attnP[2][L2N][2];               // [pos][r][hpair]
    __shared__ int idxf[100];

    const uint32_t* U  = (const uint32_t*)ws + OFF_U;
    uint32_t*       PV = (uint32_t*)wsm + OFF_PV;

    const int t = threadIdx.x, wv = t >> 6, ln = t & 63;
    const int pos0 = blockIdx.x * 2;

    // ---- Stage A: key indices + U tiles ----
    if (t < 100) idxf[t] = keys[pos0*L2N + t];
    if (t < 128) {
        uint4 uv = *(const uint4*)(U + (size_t)(pos0 + (t>>6))*256 + (t&63)*4);
        *(uint4*)&U_s[t>>6][0][0 + (t&63)*4] = uv;   // flat [4][64] = 256 u32 per pos
    }
    __syncthreads();

    // ---- Stage B: gather 100 k rows, 4-deep pipelined, f16-pack ----
    {
        #define K2LD(row) (*(const float2*)(E + (size_t)idxf[row]*DN + 2*ln))
        int r0 = wv, r1 = wv+4, r2 = wv+8, r3 = wv+12;
        float2 v0 = K2LD(r0), v1 = K2LD(r1), v2 = K2LD(r2), v3 = K2LD(r3);
        #pragma unroll 1
        for (int g = 0; g < 6; ++g) {
            int s0=r0, s1=r1, s2=r2, s3=r3;
            float2 c0=v0, c1=v1, c2=v2, c3=v3;
            r0+=16; r1+=16; r2+=16; r3+=16;
            if (g < 5) { v0=K2LD(r0); v1=K2LD(r1); v2=K2LD(r2); v3=K2LD(r3); }
            { int p=(s0>=50); kT2f[p][ln][s0-50*p] = packh2(c0.x,c0.y); }
            { int p=(s1>=50); kT2f[p][ln][s1-50*p] = packh2(c1.x,c1.y); }
            { int p=(s2>=50); kT2f[p][ln][s2-50*p] = packh2(c2.x,c2.y); }
            { int p=(s3>=50); kT2f[p][ln][s3-50*p] = packh2(c3.x,c3.y); }
        }
        int rl = wv + 96;
        float2 vl = K2LD(rl);
        { int p=(rl>=50); kT2f[p][ln][rl-50*p] = packh2(vl.x,vl.y); }
        #undef K2LD
    }
    __syncthreads();

    // ---- Stage D: scores + mask + softmax (wave = (pos, head-pair)) ----
    const int p  = wv & 1;
    const int hp = wv >> 1;
    const int h0 = 2*hp, h1 = h0 + 1;
    {
        const int r  = ln;
        const int rc = (r < L2N) ? r : 0;
        float acc0 = 0.f, acc1 = 0.f, ksum = 0.f;
        const uint32_t ONE2 = 0x3C003C00u;
        #pragma unroll 4
        for (int dp = 0; dp < 64; dp += 4) {
            uint4 u0 = *(const uint4*)&U_s[p][h0][dp];
            uint4 u1 = *(const uint4*)&U_s[p][h1][dp];
            uint32_t k0 = kT2f[p][dp+0][rc];
            uint32_t k1 = kT2f[p][dp+1][rc];
            uint32_t k2 = kT2f[p][dp+2][rc];
            uint32_t k3 = kT2f[p][dp+3][rc];
            acc0 = dot2(k0,u0.x,acc0); acc0 = dot2(k1,u0.y,acc0);
            acc0 = dot2(k2,u0.z,acc0); acc0 = dot2(k3,u0.w,acc0);
            acc1 = dot2(k0,u1.x,acc1); acc1 = dot2(k1,u1.y,acc1);
            acc1 = dot2(k2,u1.z,acc1); acc1 = dot2(k3,u1.w,acc1);
            ksum = dot2(k0,ONE2,ksum); ksum = dot2(k1,ONE2,ksum);
            ksum = dot2(k2,ONE2,ksum); ksum = dot2(k3,ONE2,ksum);
        }
        float sc0 = acc0 * 0.17677669529663687f;   // 1/sqrt(32)
        float sc1 = acc1 * 0.17677669529663687f;
        if (ksum == 0.0f) { sc0 = NEGC; sc1 = NEGC; }
        if (r >= L2N)     { sc0 = -__builtin_inff(); sc1 = -__builtin_inff(); }
        float w0, w1;
        {
            float m = sc0;
            m = fmaxf(m, __shfl_xor(m,32)); m = fmaxf(m, __shfl_xor(m,16));
            m = fmaxf(m, __shfl_xor(m, 8)); m = fmaxf(m, __shfl_xor(m, 4));
            m = fmaxf(m, __shfl_xor(m, 2)); m = fmaxf(m, __shfl_xor(m, 1));
            float e = (r < L2N) ? __expf(sc0 - m) : 0.f;
            float s = e;
            s += __shfl_xor(s,32); s += __shfl_xor(s,16); s += __shfl_xor(s,8);
            s += __shfl_xor(s, 4); s += __shfl_xor(s, 2); s += __shfl_xor(s,1);
            w0 = e / s;
        }
        {
            float m = sc1;
            m = fmaxf(m, __shfl_xor(m,32)); m = fmaxf(m, __shfl_xor(m,16));
            m = fmaxf(m, __shfl_xor(m, 8)); m = fmaxf(m, __shfl_xor(m, 4));
            m = fmaxf(m, __shfl_xor(m, 2)); m = fmaxf(m, __shfl_xor(m, 1));
            float e = (r < L2N) ? __expf(sc1 - m) : 0.f;
            float s = e;
            s += __shfl_xor(s,32); s += __shfl_xor(s,16); s += __shfl_xor(s,8);
            s += __shfl_xor(s, 4); s += __shfl_xor(s, 2); s += __shfl_xor(s,1);
            w1 = e / s;
        }
        if (r < L2N) attnP[p][r][hp] = packh2(w0, w1);
    }
    // no barrier: stage E reads only this wave's attnP + barriered kT2f

    // ---- Stage E: pv = attn^T k -> global (wave = (pos, head-pair)) ----
    {
        const int dp = ln;
        float pa0=0.f, pb0=0.f, pa1=0.f, pb1=0.f;
        #pragma unroll 2
        for (int r = 0; r < L2N; ++r) {
            uint32_t aw = attnP[p][r][hp];       // broadcast
            float w0 = lo16f(aw), w1 = hi16f(aw);
            uint32_t kp = kT2f[p][dp][r];
            float kx = lo16f(kp), ky = hi16f(kp);
            pa0 += w0*kx; pb0 += w0*ky;
            pa1 += w1*kx; pb1 += w1*ky;
        }
        uint32_t* PVp = PV + (size_t)(pos0 + p)*256;
        PVp[h0*64 + dp] = packh2(pa0, pb0);
        PVp[h1*64 + dp] = packh2(pa1, pb1);
    }
}

// ================= K3: out = PV@GT + R =================
__global__ __launch_bounds__(256, 1) void k3_out(
    const float* __restrict__ ws, float* __restrict__ out)
{
    const uint32_t* GT2 = (const uint32_t*)ws + OFF_GT2;
    const uint32_t* PV  = (const uint32_t*)ws + OFF_PV;
    const float*    R   = ws + OFF_R;

    const int t = threadIdx.x, wv = t >> 6, ln = t & 63;
    const int pg = ln >> 4, og = ln & 15;
    const int posb = blockIdx.x*64 + wv*16 + pg*4;
    const int f0 = og*8;

    float acc[4][8];
    #pragma unroll
    for (int p = 0; p < 4; ++p) {
        float4 ra = *(const float4*)(R + (size_t)(posb+p)*128 + f0);
        float4 rb = *(const float4*)(R + (size_t)(posb+p)*128 + f0 + 4);
        acc[p][0]=ra.x; acc[p][1]=ra.y; acc[p][2]=ra.z; acc[p][3]=ra.w;
        acc[p][4]=rb.x; acc[p][5]=rb.y; acc[p][6]=rb.z; acc[p][7]=rb.w;
    }
    #pragma unroll 1
    for (int j = 0; j < 256; j += 4) {
        uint4 a[4];
        #pragma unroll
        for (int p = 0; p < 4; ++p)
            a[p] = *(const uint4*)(PV + (size_t)(posb+p)*256 + j);
        #pragma unroll
        for (int jj = 0; jj < 4; ++jj) {
            uint4 g0 = *(const uint4*)(GT2 + (j+jj)*128 + f0);
            uint4 g1 = *(const uint4*)(GT2 + (j+jj)*128 + f0 + 4);
            #pragma unroll
            for (int p = 0; p < 4; ++p) {
                uint32_t ap = (jj==0)?a[p].x:(jj==1)?a[p].y:(jj==2)?a[p].z:a[p].w;
                acc[p][0] = dot2(ap, g0.x, acc[p][0]);
                acc[p][1] = dot2(ap, g0.y, acc[p][1]);
                acc[p][2] = dot2(ap, g0.z, acc[p][2]);
                acc[p][3] = dot2(ap, g0.w, acc[p][3]);
                acc[p][4] = dot2(ap, g1.x, acc[p][4]);
                acc[p][5] = dot2(ap, g1.y, acc[p][5]);
                acc[p][6] = dot2(ap, g1.z, acc[p][6]);
                acc[p][7] = dot2(ap, g1.w, acc[p][7]);
            }
        }
    }
    #pragma unroll
    for (int p = 0; p < 4; ++p) {
        float4 oa = {acc[p][0], acc[p][1], acc[p][2], acc[p][3]};
        float4 ob = {acc[p][4], acc[p][5], acc[p][6], acc[p][7]};
        *(float4*)(out + (size_t)(posb+p)*FN + f0)     = oa;
        *(float4*)(out + (size_t)(posb+p)*FN + f0 + 4) = ob;
    }
}

extern "C" void kernel_launch(void* const* d_in, const int* in_sizes, int n_in,
                              void* d_out, int out_size, void* d_ws, size_t ws_size,
                              hipStream_t stream) {
    const int* queries = (const int*)d_in[0];
    const int* keys    = (const int*)d_in[1];
    const float* E   = (const float*)d_in[2];
    const float* Wq  = (const float*)d_in[3];
    const float* bq  = (const float*)d_in[4];
    const float* Wk  = (const float*)d_in[5];
    const float* bk  = (const float*)d_in[6];
    const float* Wv  = (const float*)d_in[7];
    const float* bv  = (const float*)d_in[8];
    const float* Wf  = (const float*)d_in[9];
    const float* bfb = (const float*)d_in[10];
    float* ws = (float*)d_ws;
    float* o  = (float*)d_out;

    hipLaunchKernelGGL(k0_pre,  dim3(9),    dim3(256), 0, stream,
                       Wq, bq, Wk, bk, Wv, bv, Wf, bfb, ws);
    hipLaunchKernelGGL(k1_proj, dim3(200),  dim3(256), 0, stream, queries, E, ws);
    hipLaunchKernelGGL(k2_attn, dim3(6400), dim3(256), 0, stream, keys, E, ws, ws);
    hipLaunchKernelGGL(k3_out,  dim3(200),  dim3(256), 0, stream, ws, o);
}

// Round 6
// 255.796 us; speedup vs baseline: 2.2845x; 1.1811x over previous
//
#include <hip/hip_runtime.h>
#include <stdint.h>

#define DN 128
#define AN 128
#define HN 4
#define FN 128
#define L2N 50
#define NPOS (64*200)
#define NEGC (-4294967295.0f)

// ws layout (4B units)
#define OFF_MTW2 0         // u32 [64 dd2][640]  : cols 0..511 = MT pairs(dd), 512..639 = Wf pairs(dd)
#define OFF_GT2  40960     // u32 [256 j][128 f] : half2(GT[2j][f],GT[2j+1][f]), j = h*64 + dpair
#define OFF_CB   73728     // f32 [640]          : 0..511 = Wk_h^T bq ; 512..639 = bv@Wf+bf
#define OFF_U    74368     // u32 [12800][256]   : u as half2 pairs along outc
#define OFF_R    3351168   // f32 [12800][128]   : qe@Wf + B0
#define OFF_PV   4989568   // u32 [12800][256]   : pv as half2 pairs, flat [4h][64 dpair]

typedef __fp16 half2v __attribute__((ext_vector_type(2)));

__device__ __forceinline__ float dot2(uint32_t a, uint32_t b, float c) {
#if __has_builtin(__builtin_amdgcn_fdot2)
    union { uint32_t u; half2v h; } ca, cb; ca.u = a; cb.u = b;
    return __builtin_amdgcn_fdot2(ca.h, cb.h, c, false);
#else
    union { uint32_t u; _Float16 h[2]; } ca, cb; ca.u = a; cb.u = b;
    return c + (float)ca.h[0]*(float)cb.h[0] + (float)ca.h[1]*(float)cb.h[1];
#endif
}
__device__ __forceinline__ uint32_t packh2(float x, float y) {   // RTNE
    union { _Float16 h[2]; uint32_t u; } c; c.h[0] = (_Float16)x; c.h[1] = (_Float16)y;
    return c.u;
}
__device__ __forceinline__ float lo16f(uint32_t u) {
    union { uint32_t u; _Float16 h[2]; } c; c.u = u; return (float)c.h[0];
}
__device__ __forceinline__ float hi16f(uint32_t u) {
    union { uint32_t u; _Float16 h[2]; } c; c.u = u; return (float)c.h[1];
}

// ================= K0: fold weights, 1 thread per output (291 blocks) =================
__global__ __launch_bounds__(256) void k0_pre(
    const float* __restrict__ Wq, const float* __restrict__ bq,
    const float* __restrict__ Wk, const float* __restrict__ bk,
    const float* __restrict__ Wv, const float* __restrict__ bv,
    const float* __restrict__ Wf, const float* __restrict__ bfb,
    float* __restrict__ ws)
{
    uint32_t* MTW2 = (uint32_t*)ws + OFF_MTW2;
    uint32_t* GT2w = (uint32_t*)ws + OFF_GT2;
    float*    CB   = ws + OFF_CB;
    const int idx = blockIdx.x*256 + threadIdx.x;

    if (idx < 32768) {                       // MT[dd2][col]: pairs along dd
        int dd2 = idx >> 9, col = idx & 511;
        int h = col >> 7, d = col & 127;
        const float* wq0 = Wq + (2*dd2)*AN + h*32;
        const float* wq1 = Wq + (2*dd2+1)*AN + h*32;
        const float* wk  = Wk + d*AN + h*32;
        float s0 = 0.f, s1 = 0.f;
        #pragma unroll 8
        for (int j = 0; j < 32; ++j) { float w = wk[j]; s0 += wq0[j]*w; s1 += wq1[j]*w; }
        MTW2[dd2*640 + col] = packh2(s0, s1);
    } else if (idx < 65536) {                // GT2[j][f]: pairs along d
        int i2 = idx - 32768;
        int j = i2 >> 7, f = i2 & 127;
        int h = j >> 6, d = 2*(j & 63);
        const float* wv0 = Wv + d*AN + h*32;
        const float* wv1 = Wv + (d+1)*AN + h*32;
        float s0 = 0.f, s1 = 0.f;
        #pragma unroll 8
        for (int a = 0; a < 32; ++a) {
            float wf = Wf[(h*32+a)*FN + f];
            s0 += wv0[a]*wf; s1 += wv1[a]*wf;
        }
        GT2w[j*128 + f] = packh2(s0, s1);
    } else if (idx < 73728) {                // Wf pairs -> MTW2 cols 512..639
        int i3 = idx - 65536;
        int dd2 = i3 >> 7, f = i3 & 127;
        MTW2[dd2*640 + 512 + f] = packh2(Wf[(2*dd2)*FN + f], Wf[(2*dd2+1)*FN + f]);
    } else {                                 // CB (640 entries over 3 blocks)
        int c = idx - 73728;
        if (c < 512) {                       // Wk_h^T bq
            int h = c >> 7, d = c & 127;
            float s = 0.f;
            #pragma unroll 8
            for (int j = 0; j < 32; ++j) s += Wk[d*AN + h*32 + j]*bq[h*32 + j];
            CB[c] = s;
        } else if (c < 640) {                // B0 = bv@Wf + bf
            int f = c - 512;
            float s = bfb[f];
            for (int a = 0; a < AN; ++a) s += bv[a]*Wf[a*FN + f];
            CB[c] = s;
        }
    }
}

// ================= K1: U = qe@MT + C ; R = qe@Wf + B0 (1000 blocks) =================
__global__ __launch_bounds__(256) void k1_proj(
    const int* __restrict__ queries, const float* __restrict__ E,
    float* __restrict__ ws)
{
    const uint32_t* MTW2 = (const uint32_t*)ws + OFF_MTW2;
    const float*    CB   = ws + OFF_CB;
    uint32_t* U = (uint32_t*)ws + OFF_U;
    float*    R = ws + OFF_R;

    const int b = blockIdx.x;
    const int pb = b / 5, pass = b - pb*5;
    const int t = threadIdx.x, wv = t >> 6, ln = t & 63;
    const int pg = ln >> 4, og = ln & 15;
    const int posb = pb*64 + wv*16 + pg*4;
    const int outc0 = pass*128 + og*8;

    const float* eq[4];
    #pragma unroll
    for (int p = 0; p < 4; ++p)
        eq[p] = E + (size_t)queries[posb + p] * DN;

    float acc[4][8];
    float4 b0 = *(const float4*)(CB + outc0);
    float4 b1 = *(const float4*)(CB + outc0 + 4);
    #pragma unroll
    for (int p = 0; p < 4; ++p) {
        acc[p][0]=b0.x; acc[p][1]=b0.y; acc[p][2]=b0.z; acc[p][3]=b0.w;
        acc[p][4]=b1.x; acc[p][5]=b1.y; acc[p][6]=b1.z; acc[p][7]=b1.w;
    }
    #pragma unroll 4
    for (int dd2 = 0; dd2 < 64; ++dd2) {
        uint4 m0 = *(const uint4*)(MTW2 + dd2*640 + outc0);
        uint4 m1 = *(const uint4*)(MTW2 + dd2*640 + outc0 + 4);
        #pragma unroll
        for (int p = 0; p < 4; ++p) {
            float2 q2 = *(const float2*)(eq[p] + 2*dd2);
            uint32_t qp = packh2(q2.x, q2.y);
            acc[p][0] = dot2(qp, m0.x, acc[p][0]);
            acc[p][1] = dot2(qp, m0.y, acc[p][1]);
            acc[p][2] = dot2(qp, m0.z, acc[p][2]);
            acc[p][3] = dot2(qp, m0.w, acc[p][3]);
            acc[p][4] = dot2(qp, m1.x, acc[p][4]);
            acc[p][5] = dot2(qp, m1.y, acc[p][5]);
            acc[p][6] = dot2(qp, m1.z, acc[p][6]);
            acc[p][7] = dot2(qp, m1.w, acc[p][7]);
        }
    }
    if (pass < 4) {
        #pragma unroll
        for (int p = 0; p < 4; ++p) {
            uint4 up;
            up.x = packh2(acc[p][0], acc[p][1]);
            up.y = packh2(acc[p][2], acc[p][3]);
            up.z = packh2(acc[p][4], acc[p][5]);
            up.w = packh2(acc[p][6], acc[p][7]);
            *(uint4*)(U + (size_t)(posb+p)*256 + pass*64 + og*4) = up;
        }
    } else {
        const int f = og*8;
        #pragma unroll
        for (int p = 0; p < 4; ++p) {
            float4 ra = {acc[p][0], acc[p][1], acc[p][2], acc[p][3]};
            float4 rb = {acc[p][4], acc[p][5], acc[p][6], acc[p][7]};
            *(float4*)(R + (size_t)(posb+p)*128 + f)     = ra;
            *(float4*)(R + (size_t)(posb+p)*128 + f + 4) = rb;
        }
    }
}

// ================= K2: attention core — 1 wave per position, k held in regs =================
__global__ __launch_bounds__(128) void k2_attn(
    const int* __restrict__ keys, const float* __restrict__ E,
    float* __restrict__ ws)
{
    __shared__ __align__(16) uint32_t kT[2][64][51];   // half2(k[2dp],k[2dp+1]) [pos][dp][r]
    __shared__ __align__(16) uint32_t U_s[2][256];     // u pairs, flat [4h][64dp]
    __shared__ __align__(8)  uint32_t attnT[2][L2N][2];// per r: {h2(w0,w1), h2(w2,w3)}

    const uint32_t* U  = (const uint32_t*)ws + OFF_U;
    uint32_t*       PV = (uint32_t*)ws + OFF_PV;

    const int t = threadIdx.x, wv = t >> 6, ln = t & 63;
    const int pos0 = blockIdx.x * 2;

    // ---- Stage A: stage U for both positions (128 uint4) ----
    ((uint4*)&U_s[0][0])[t] = ((const uint4*)(U + (size_t)pos0*256))[t];

    // ---- Stage B: gather 50 k rows for THIS wave's position; lane = d-pair.
    //      Keep each lane's pair in registers for stage E; also write kT for stage D.
    const int* kptr = keys + (size_t)(pos0 + wv)*L2N;
    uint32_t kreg[L2N];
    {
        float2 f0 = *(const float2*)(E + (size_t)kptr[0]*DN + 2*ln);
        float2 f1 = *(const float2*)(E + (size_t)kptr[1]*DN + 2*ln);
        float2 f2 = *(const float2*)(E + (size_t)kptr[2]*DN + 2*ln);
        float2 f3 = *(const float2*)(E + (size_t)kptr[3]*DN + 2*ln);
        #pragma unroll
        for (int r = 0; r < L2N; ++r) {
            float2 cur;
            if ((r&3)==0) cur=f0; else if ((r&3)==1) cur=f1; else if ((r&3)==2) cur=f2; else cur=f3;
            if (r+4 < L2N) {
                float2 nx = *(const float2*)(E + (size_t)kptr[r+4]*DN + 2*ln);
                if ((r&3)==0) f0=nx; else if ((r&3)==1) f1=nx; else if ((r&3)==2) f2=nx; else f3=nx;
            }
            uint32_t u = packh2(cur.x, cur.y);
            kreg[r] = u;
            kT[wv][ln][r] = u;
        }
    }
    __syncthreads();   // covers U_s (cross-wave) and kT (cross-lane)

    // ---- Stage D: scores + mask + softmax. lane = r, all 4 heads in-wave ----
    {
        const int r  = ln;
        const int rc = (r < L2N) ? r : 0;
        float acc0=0.f, acc1=0.f, acc2=0.f, acc3=0.f, ksum=0.f;
        const uint32_t ONE2 = 0x3C003C00u;
        #pragma unroll 4
        for (int dp = 0; dp < 64; dp += 4) {
            uint4 u0 = *(const uint4*)&U_s[wv][0*64 + dp];
            uint4 u1 = *(const uint4*)&U_s[wv][1*64 + dp];
            uint4 u2 = *(const uint4*)&U_s[wv][2*64 + dp];
            uint4 u3 = *(const uint4*)&U_s[wv][3*64 + dp];
            uint32_t k0 = kT[wv][dp+0][rc];
            uint32_t k1 = kT[wv][dp+1][rc];
            uint32_t k2 = kT[wv][dp+2][rc];
            uint32_t k3 = kT[wv][dp+3][rc];
            acc0 = dot2(k0,u0.x,acc0); acc0 = dot2(k1,u0.y,acc0);
            acc0 = dot2(k2,u0.z,acc0); acc0 = dot2(k3,u0.w,acc0);
            acc1 = dot2(k0,u1.x,acc1); acc1 = dot2(k1,u1.y,acc1);
            acc1 = dot2(k2,u1.z,acc1); acc1 = dot2(k3,u1.w,acc1);
            acc2 = dot2(k0,u2.x,acc2); acc2 = dot2(k1,u2.y,acc2);
            acc2 = dot2(k2,u2.z,acc2); acc2 = dot2(k3,u2.w,acc2);
            acc3 = dot2(k0,u3.x,acc3); acc3 = dot2(k1,u3.y,acc3);
            acc3 = dot2(k2,u3.z,acc3); acc3 = dot2(k3,u3.w,acc3);
            ksum = dot2(k0,ONE2,ksum); ksum = dot2(k1,ONE2,ksum);
            ksum = dot2(k2,ONE2,ksum); ksum = dot2(k3,ONE2,ksum);
        }
        float sc[4];
        sc[0] = acc0 * 0.17677669529663687f;   // 1/sqrt(32); softmax shift-invariant consts dropped
        sc[1] = acc1 * 0.17677669529663687f;
        sc[2] = acc2 * 0.17677669529663687f;
        sc[3] = acc3 * 0.17677669529663687f;
        if (ksum == 0.0f) { sc[0]=NEGC; sc[1]=NEGC; sc[2]=NEGC; sc[3]=NEGC; }
        if (r >= L2N) { sc[0]=-__builtin_inff(); sc[1]=-__builtin_inff();
                        sc[2]=-__builtin_inff(); sc[3]=-__builtin_inff(); }
        float w[4];
        #pragma unroll
        for (int h = 0; h < 4; ++h) {
            float m = sc[h];
            m = fmaxf(m, __shfl_xor(m,32)); m = fmaxf(m, __shfl_xor(m,16));
            m = fmaxf(m, __shfl_xor(m, 8)); m = fmaxf(m, __shfl_xor(m, 4));
            m = fmaxf(m, __shfl_xor(m, 2)); m = fmaxf(m, __shfl_xor(m, 1));
            float e = (r < L2N) ? __expf(sc[h] - m) : 0.f;
            float s = e;
            s += __shfl_xor(s,32); s += __shfl_xor(s,16); s += __shfl_xor(s,8);
            s += __shfl_xor(s, 4); s += __shfl_xor(s, 2); s += __shfl_xor(s,1);
            w[h] = e / s;
        }
        if (r < L2N) {
            attnT[wv][r][0] = packh2(w[0], w[1]);
            attnT[wv][r][1] = packh2(w[2], w[3]);
        }
    }
    __syncthreads();

    // ---- Stage E: pv from registers; only attn weights come from LDS ----
    {
        float pa0=0.f,pb0=0.f,pa1=0.f,pb1=0.f,pa2=0.f,pb2=0.f,pa3=0.f,pb3=0.f;
        #pragma unroll
        for (int r = 0; r < L2N; ++r) {
            uint2 aw = *(const uint2*)&attnT[wv][r][0];   // broadcast
            float w0 = lo16f(aw.x), w1 = hi16f(aw.x);
            float w2 = lo16f(aw.y), w3 = hi16f(aw.y);
            uint32_t kp = kreg[r];
            float kx = lo16f(kp), ky = hi16f(kp);
            pa0 += w0*kx; pb0 += w0*ky;
            pa1 += w1*kx; pb1 += w1*ky;
            pa2 += w2*kx; pb2 += w2*ky;
            pa3 += w3*kx; pb3 += w3*ky;
        }
        uint32_t* PVp = PV + (size_t)(pos0 + wv)*256;
        PVp[0*64 + ln] = packh2(pa0, pb0);
        PVp[1*64 + ln] = packh2(pa1, pb1);
        PVp[2*64 + ln] = packh2(pa2, pb2);
        PVp[3*64 + ln] = packh2(pa3, pb3);
    }
}

// ================= K3: out = PV@GT + R (800 blocks, 1 pos/thread) =================
__global__ __launch_bounds__(256) void k3_out(
    const float* __restrict__ ws, float* __restrict__ out)
{
    const uint32_t* GT2 = (const uint32_t*)ws + OFF_GT2;
    const uint32_t* PV  = (const uint32_t*)ws + OFF_PV;
    const float*    R   = ws + OFF_R;

    const int t = threadIdx.x, wv = t >> 6, ln = t & 63;
    const int pg = ln >> 4, og = ln & 15;
    const int pos = blockIdx.x*16 + wv*4 + pg;
    const int f0 = og*8;

    float acc[8];
    {
        float4 ra = *(const float4*)(R + (size_t)pos*128 + f0);
        float4 rb = *(const float4*)(R + (size_t)pos*128 + f0 + 4);
        acc[0]=ra.x; acc[1]=ra.y; acc[2]=ra.z; acc[3]=ra.w;
        acc[4]=rb.x; acc[5]=rb.y; acc[6]=rb.z; acc[7]=rb.w;
    }
    const uint32_t* PVp = PV + (size_t)pos*256;
    #pragma unroll 1
    for (int j = 0; j < 256; j += 4) {
        uint4 a = *(const uint4*)(PVp + j);               // broadcast across og
        #pragma unroll
        for (int jj = 0; jj < 4; ++jj) {
            uint4 g0 = *(const uint4*)(GT2 + (j+jj)*128 + f0);
            uint4 g1 = *(const uint4*)(GT2 + (j+jj)*128 + f0 + 4);
            uint32_t ap = (jj==0)?a.x:(jj==1)?a.y:(jj==2)?a.z:a.w;
            acc[0] = dot2(ap, g0.x, acc[0]);
            acc[1] = dot2(ap, g0.y, acc[1]);
            acc[2] = dot2(ap, g0.z, acc[2]);
            acc[3] = dot2(ap, g0.w, acc[3]);
            acc[4] = dot2(ap, g1.x, acc[4]);
            acc[5] = dot2(ap, g1.y, acc[5]);
            acc[6] = dot2(ap, g1.z, acc[6]);
            acc[7] = dot2(ap, g1.w, acc[7]);
        }
    }
    float4 oa = {acc[0], acc[1], acc[2], acc[3]};
    float4 ob = {acc[4], acc[5], acc[6], acc[7]};
    *(float4*)(out + (size_t)pos*FN + f0)     = oa;
    *(float4*)(out + (size_t)pos*FN + f0 + 4) = ob;
}

extern "C" void kernel_launch(void* const* d_in, const int* in_sizes, int n_in,
                              void* d_out, int out_size, void* d_ws, size_t ws_size,
                              hipStream_t stream) {
    const int* queries = (const int*)d_in[0];
    const int* keys    = (const int*)d_in[1];
    const float* E   = (const float*)d_in[2];
    const float* Wq  = (const float*)d_in[3];
    const float* bq  = (const float*)d_in[4];
    const float* Wk  = (const float*)d_in[5];
    const float* bk  = (const float*)d_in[6];
    const float* Wv  = (const float*)d_in[7];
    const float* bv  = (const float*)d_in[8];
    const float* Wf  = (const float*)d_in[9];
    const float* bfb = (const float*)d_in[10];
    float* ws = (float*)d_ws;
    float* o  = (float*)d_out;

    hipLaunchKernelGGL(k0_pre,  dim3(291),  dim3(256), 0, stream,
                       Wq, bq, Wk, bk, Wv, bv, Wf, bfb, ws);
    hipLaunchKernelGGL(k1_proj, dim3(1000), dim3(256), 0, stream, queries, E, ws);
    hipLaunchKernelGGL(k2_attn, dim3(6400), dim3(128), 0, stream, keys, E, ws);
    hipLaunchKernelGGL(k3_out,  dim3(800),  dim3(256), 0, stream, ws, o);
}

// Round 7
// 185.783 us; speedup vs baseline: 3.1454x; 1.3769x over previous
//
#include <hip/hip_runtime.h>
#include <stdint.h>

#define DN 128
#define AN 128
#define HN 4
#define FN 128
#define L2N 50
#define NPOS (64*200)
#define NEGC (-4294967295.0f)

// ws layout (4B units)
#define OFF_MTWB 0         // u32 [40 tn][4 kk][64 lane][4 jj] : B-frag MT|Wf pairs along dd
#define OFF_GTB  40960     // u32 [8 tn][16 kk][64 lane][4 jj] : B-frag GT pairs along flat hd
#define OFF_CB   73728     // f32 [640] : 0..511 = Wk_h^T bq ; 512..639 = bv@Wf+bf
#define OFF_U    74368     // u32 [12800][256] : u as half2 pairs along outc
#define OFF_R    3351168   // f32 [12800][128] : qe@Wf + B0
#define OFF_PV   4989568   // u32 [12800][256] : pv as half2 pairs, flat hd

typedef __fp16 half2v __attribute__((ext_vector_type(2)));
typedef __fp16 f16x8  __attribute__((ext_vector_type(8)));
typedef float  f32x4  __attribute__((ext_vector_type(4)));
union frg { uint4 u; f16x8 h; };

__device__ __forceinline__ float dot2(uint32_t a, uint32_t b, float c) {
#if __has_builtin(__builtin_amdgcn_fdot2)
    union { uint32_t u; half2v h; } ca, cb; ca.u = a; cb.u = b;
    return __builtin_amdgcn_fdot2(ca.h, cb.h, c, false);
#else
    union { uint32_t u; _Float16 h[2]; } ca, cb; ca.u = a; cb.u = b;
    return c + (float)ca.h[0]*(float)cb.h[0] + (float)ca.h[1]*(float)cb.h[1];
#endif
}
__device__ __forceinline__ uint32_t packh2(float x, float y) {   // RTNE
    union { _Float16 h[2]; uint32_t u; } c; c.h[0] = (_Float16)x; c.h[1] = (_Float16)y;
    return c.u;
}
__device__ __forceinline__ float lo16f(uint32_t u) {
    union { uint32_t u; _Float16 h[2]; } c; c.u = u; return (float)c.h[0];
}
__device__ __forceinline__ float hi16f(uint32_t u) {
    union { uint32_t u; _Float16 h[2]; } c; c.u = u; return (float)c.h[1];
}

// ================= K0: fold weights into MFMA-B-fragment order =================
__global__ __launch_bounds__(256) void k0_pre(
    const float* __restrict__ Wq, const float* __restrict__ bq,
    const float* __restrict__ Wk, const float* __restrict__ bk,
    const float* __restrict__ Wv, const float* __restrict__ bv,
    const float* __restrict__ Wf, const float* __restrict__ bfb,
    float* __restrict__ ws)
{
    uint32_t* MTWB = (uint32_t*)ws + OFF_MTWB;
    uint32_t* GTBw = (uint32_t*)ws + OFF_GTB;
    float*    CB   = ws + OFF_CB;
    const int idx = blockIdx.x*256 + threadIdx.x;

    if (idx < 40960) {                       // MTWB: pairs along dd
        int jj = idx & 3, lane = (idx>>2)&63, kk = (idx>>8)&3, tn = idx>>10;
        int outc = tn*16 + (lane&15);
        int dd2  = kk*16 + (lane>>4)*4 + jj;
        int dd0  = 2*dd2, dd1 = dd0+1;
        float s0, s1;
        if (outc < 512) {                    // MT[dd][outc] = Wq[dd]_h . Wk[d]_h
            int h = outc >> 7, d = outc & 127;
            const float* wk = Wk + d*AN + h*32;
            const float* q0 = Wq + dd0*AN + h*32;
            const float* q1 = Wq + dd1*AN + h*32;
            s0 = 0.f; s1 = 0.f;
            #pragma unroll 8
            for (int j = 0; j < 32; ++j) { float w = wk[j]; s0 += q0[j]*w; s1 += q1[j]*w; }
        } else {                             // Wf[dd][f]
            int f = outc - 512;
            s0 = Wf[dd0*FN + f]; s1 = Wf[dd1*FN + f];
        }
        MTWB[idx] = packh2(s0, s1);
    } else if (idx < 73728) {                // GTB: pairs along flat hd
        int i2 = idx - 40960;
        int jj = i2 & 3, lane = (i2>>2)&63, kk = (i2>>8)&15, tn = i2>>12;
        int f  = tn*16 + (lane&15);
        int j2 = kk*16 + (lane>>4)*4 + jj;
        int hd0 = 2*j2;
        int h = hd0 >> 7, d0 = hd0 & 127, d1 = d0+1;
        const float* v0 = Wv + d0*AN + h*32;
        const float* v1 = Wv + d1*AN + h*32;
        float s0 = 0.f, s1 = 0.f;
        #pragma unroll 8
        for (int a = 0; a < 32; ++a) {
            float wf = Wf[(h*32+a)*FN + f];
            s0 += v0[a]*wf; s1 += v1[a]*wf;
        }
        GTBw[i2] = packh2(s0, s1);
    } else {                                 // CB
        int c = idx - 73728;
        if (c < 512) {                       // Wk_h^T bq
            int h = c >> 7, d = c & 127;
            float s = 0.f;
            #pragma unroll 8
            for (int j = 0; j < 32; ++j) s += Wk[d*AN + h*32 + j]*bq[h*32 + j];
            CB[c] = s;
        } else if (c < 640) {                // B0 = bv@Wf + bf
            int f = c - 512;
            float s = bfb[f];
            for (int a = 0; a < AN; ++a) s += bv[a]*Wf[a*FN + f];
            CB[c] = s;
        }
    }
}

// ================= K1: MFMA GEMM  U|R = qe @ [MT|Wf] + CB =================
__global__ __launch_bounds__(256) void k1_proj(
    const int* __restrict__ queries, const float* __restrict__ E,
    float* __restrict__ ws)
{
    const uint32_t* MTWB = (const uint32_t*)ws + OFF_MTWB;
    const float*    CB   = ws + OFF_CB;
    uint32_t* U = (uint32_t*)ws + OFF_U;
    float*    R = ws + OFF_R;

    const int t = threadIdx.x, wv = t >> 6, ln = t & 63;
    const int W  = blockIdx.x*4 + wv;          // 4000 waves
    const int tm = W / 5, g = W - tm*5;        // m-tile, n-group (8 tiles)
    const int m = ln & 15, q = ln >> 4;
    const int pos0 = tm*16 + q*4;

    const int qidx = queries[tm*16 + m];
    const float* Eq = E + (size_t)qidx * DN;

    frg a[4];
    #pragma unroll
    for (int kk = 0; kk < 4; ++kk) {           // A-frag: lane m=row, q*8 k-offset
        float4 e0 = *(const float4*)(Eq + kk*32 + q*8);
        float4 e1 = *(const float4*)(Eq + kk*32 + q*8 + 4);
        a[kk].u.x = packh2(e0.x, e0.y);
        a[kk].u.y = packh2(e0.z, e0.w);
        a[kk].u.z = packh2(e1.x, e1.y);
        a[kk].u.w = packh2(e1.z, e1.w);
    }

    #pragma unroll 1
    for (int i = 0; i < 8; ++i) {
        const int tn = g*8 + i;
        const float cb = CB[tn*16 + m];
        f32x4 c = {cb, cb, cb, cb};
        #pragma unroll
        for (int kk = 0; kk < 4; ++kk) {
            frg b; b.u = *(const uint4*)(MTWB + ((size_t)(tn*4 + kk)*64 + ln)*4);
            c = __builtin_amdgcn_mfma_f32_16x16x32_f16(a[kk].h, b.h, c, 0, 0, 0);
        }
        if (tn < 32) {                         // U: pack (outc,outc+1) via lane^1
            float p0 = __shfl_xor(c[0], 1);
            float p1 = __shfl_xor(c[1], 1);
            float p2 = __shfl_xor(c[2], 1);
            float p3 = __shfl_xor(c[3], 1);
            if ((ln & 1) == 0) {
                const int ucol = tn*8 + (m >> 1);
                U[(size_t)(pos0+0)*256 + ucol] = packh2(c[0], p0);
                U[(size_t)(pos0+1)*256 + ucol] = packh2(c[1], p1);
                U[(size_t)(pos0+2)*256 + ucol] = packh2(c[2], p2);
                U[(size_t)(pos0+3)*256 + ucol] = packh2(c[3], p3);
            }
        } else {                               // R: f32, D-layout
            const int f = (tn - 32)*16 + m;
            R[(size_t)(pos0+0)*128 + f] = c[0];
            R[(size_t)(pos0+1)*128 + f] = c[1];
            R[(size_t)(pos0+2)*128 + f] = c[2];
            R[(size_t)(pos0+3)*128 + f] = c[3];
        }
    }
}

// ================= K2: attention core — 1 wave per position (unchanged) =================
__global__ __launch_bounds__(128) void k2_attn(
    const int* __restrict__ keys, const float* __restrict__ E,
    float* __restrict__ ws)
{
    __shared__ __align__(16) uint32_t kT[2][64][51];
    __shared__ __align__(16) uint32_t U_s[2][256];
    __shared__ __align__(8)  uint32_t attnT[2][L2N][2];

    const uint32_t* U  = (const uint32_t*)ws + OFF_U;
    uint32_t*       PV = (uint32_t*)ws + OFF_PV;

    const int t = threadIdx.x, wv = t >> 6, ln = t & 63;
    const int pos0 = blockIdx.x * 2;

    ((uint4*)&U_s[0][0])[t] = ((const uint4*)(U + (size_t)pos0*256))[t];

    const int* kptr = keys + (size_t)(pos0 + wv)*L2N;
    uint32_t kreg[L2N];
    {
        float2 f0 = *(const float2*)(E + (size_t)kptr[0]*DN + 2*ln);
        float2 f1 = *(const float2*)(E + (size_t)kptr[1]*DN + 2*ln);
        float2 f2 = *(const float2*)(E + (size_t)kptr[2]*DN + 2*ln);
        float2 f3 = *(const float2*)(E + (size_t)kptr[3]*DN + 2*ln);
        #pragma unroll
        for (int r = 0; r < L2N; ++r) {
            float2 cur;
            if ((r&3)==0) cur=f0; else if ((r&3)==1) cur=f1; else if ((r&3)==2) cur=f2; else cur=f3;
            if (r+4 < L2N) {
                float2 nx = *(const float2*)(E + (size_t)kptr[r+4]*DN + 2*ln);
                if ((r&3)==0) f0=nx; else if ((r&3)==1) f1=nx; else if ((r&3)==2) f2=nx; else f3=nx;
            }
            uint32_t u = packh2(cur.x, cur.y);
            kreg[r] = u;
            kT[wv][ln][r] = u;
        }
    }
    __syncthreads();

    {
        const int r  = ln;
        const int rc = (r < L2N) ? r : 0;
        float acc0=0.f, acc1=0.f, acc2=0.f, acc3=0.f, ksum=0.f;
        const uint32_t ONE2 = 0x3C003C00u;
        #pragma unroll 4
        for (int dp = 0; dp < 64; dp += 4) {
            uint4 u0 = *(const uint4*)&U_s[wv][0*64 + dp];
            uint4 u1 = *(const uint4*)&U_s[wv][1*64 + dp];
            uint4 u2 = *(const uint4*)&U_s[wv][2*64 + dp];
            uint4 u3 = *(const uint4*)&U_s[wv][3*64 + dp];
            uint32_t k0 = kT[wv][dp+0][rc];
            uint32_t k1 = kT[wv][dp+1][rc];
            uint32_t k2 = kT[wv][dp+2][rc];
            uint32_t k3 = kT[wv][dp+3][rc];
            acc0 = dot2(k0,u0.x,acc0); acc0 = dot2(k1,u0.y,acc0);
            acc0 = dot2(k2,u0.z,acc0); acc0 = dot2(k3,u0.w,acc0);
            acc1 = dot2(k0,u1.x,acc1); acc1 = dot2(k1,u1.y,acc1);
            acc1 = dot2(k2,u1.z,acc1); acc1 = dot2(k3,u1.w,acc1);
            acc2 = dot2(k0,u2.x,acc2); acc2 = dot2(k1,u2.y,acc2);
            acc2 = dot2(k2,u2.z,acc2); acc2 = dot2(k3,u2.w,acc2);
            acc3 = dot2(k0,u3.x,acc3); acc3 = dot2(k1,u3.y,acc3);
            acc3 = dot2(k2,u3.z,acc3); acc3 = dot2(k3,u3.w,acc3);
            ksum = dot2(k0,ONE2,ksum); ksum = dot2(k1,ONE2,ksum);
            ksum = dot2(k2,ONE2,ksum); ksum = dot2(k3,ONE2,ksum);
        }
        float sc[4];
        sc[0] = acc0 * 0.17677669529663687f;
        sc[1] = acc1 * 0.17677669529663687f;
        sc[2] = acc2 * 0.17677669529663687f;
        sc[3] = acc3 * 0.17677669529663687f;
        if (ksum == 0.0f) { sc[0]=NEGC; sc[1]=NEGC; sc[2]=NEGC; sc[3]=NEGC; }
        if (r >= L2N) { sc[0]=-__builtin_inff(); sc[1]=-__builtin_inff();
                        sc[2]=-__builtin_inff(); sc[3]=-__builtin_inff(); }
        float w[4];
        #pragma unroll
        for (int h = 0; h < 4; ++h) {
            float m = sc[h];
            m = fmaxf(m, __shfl_xor(m,32)); m = fmaxf(m, __shfl_xor(m,16));
            m = fmaxf(m, __shfl_xor(m, 8)); m = fmaxf(m, __shfl_xor(m, 4));
            m = fmaxf(m, __shfl_xor(m, 2)); m = fmaxf(m, __shfl_xor(m, 1));
            float e = (r < L2N) ? __expf(sc[h] - m) : 0.f;
            float s = e;
            s += __shfl_xor(s,32); s += __shfl_xor(s,16); s += __shfl_xor(s,8);
            s += __shfl_xor(s, 4); s += __shfl_xor(s, 2); s += __shfl_xor(s,1);
            w[h] = e / s;
        }
        if (r < L2N) {
            attnT[wv][r][0] = packh2(w[0], w[1]);
            attnT[wv][r][1] = packh2(w[2], w[3]);
        }
    }
    __syncthreads();

    {
        float pa0=0.f,pb0=0.f,pa1=0.f,pb1=0.f,pa2=0.f,pb2=0.f,pa3=0.f,pb3=0.f;
        #pragma unroll
        for (int r = 0; r < L2N; ++r) {
            uint2 aw = *(const uint2*)&attnT[wv][r][0];
            float w0 = lo16f(aw.x), w1 = hi16f(aw.x);
            float w2 = lo16f(aw.y), w3 = hi16f(aw.y);
            uint32_t kp = kreg[r];
            float kx = lo16f(kp), ky = hi16f(kp);
            pa0 += w0*kx; pb0 += w0*ky;
            pa1 += w1*kx; pb1 += w1*ky;
            pa2 += w2*kx; pb2 += w2*ky;
            pa3 += w3*kx; pb3 += w3*ky;
        }
        uint32_t* PVp = PV + (size_t)(pos0 + wv)*256;
        PVp[0*64 + ln] = packh2(pa0, pb0);
        PVp[1*64 + ln] = packh2(pa1, pb1);
        PVp[2*64 + ln] = packh2(pa2, pb2);
        PVp[3*64 + ln] = packh2(pa3, pb3);
    }
}

// ================= K3: MFMA GEMM  out = PV @ GT + R =================
__global__ __launch_bounds__(256) void k3_out(
    const float* __restrict__ ws, float* __restrict__ out)
{
    const uint32_t* GTB = (const uint32_t*)ws + OFF_GTB;
    const uint32_t* PV  = (const uint32_t*)ws + OFF_PV;
    const float*    R   = ws + OFF_R;

    const int t = threadIdx.x, wv = t >> 6, ln = t & 63;
    const int W  = blockIdx.x*4 + wv;          // 3200 waves
    const int tm = W >> 2, g = W & 3;          // m-tile, n-group (2 tiles)
    const int m = ln & 15, q = ln >> 4;
    const int pos0 = tm*16 + q*4;

    frg a[16];
    const uint32_t* PVa = PV + (size_t)(tm*16 + m)*256;
    #pragma unroll
    for (int kk = 0; kk < 16; ++kk)
        a[kk].u = *(const uint4*)(PVa + kk*16 + q*4);

    #pragma unroll 1
    for (int i = 0; i < 2; ++i) {
        const int nt = g*2 + i;
        const int f = nt*16 + m;
        f32x4 c;
        c[0] = R[(size_t)(pos0+0)*128 + f];
        c[1] = R[(size_t)(pos0+1)*128 + f];
        c[2] = R[(size_t)(pos0+2)*128 + f];
        c[3] = R[(size_t)(pos0+3)*128 + f];
        #pragma unroll
        for (int kk = 0; kk < 16; ++kk) {
            frg b; b.u = *(const uint4*)(GTB + ((size_t)(nt*16 + kk)*64 + ln)*4);
            c = __builtin_amdgcn_mfma_f32_16x16x32_f16(a[kk].h, b.h, c, 0, 0, 0);
        }
        out[(size_t)(pos0+0)*128 + f] = c[0];
        out[(size_t)(pos0+1)*128 + f] = c[1];
        out[(size_t)(pos0+2)*128 + f] = c[2];
        out[(size_t)(pos0+3)*128 + f] = c[3];
    }
}

extern "C" void kernel_launch(void* const* d_in, const int* in_sizes, int n_in,
                              void* d_out, int out_size, void* d_ws, size_t ws_size,
                              hipStream_t stream) {
    const int* queries = (const int*)d_in[0];
    const int* keys    = (const int*)d_in[1];
    const float* E   = (const float*)d_in[2];
    const float* Wq  = (const float*)d_in[3];
    const float* bq  = (const float*)d_in[4];
    const float* Wk  = (const float*)d_in[5];
    const float* bk  = (const float*)d_in[6];
    const float* Wv  = (const float*)d_in[7];
    const float* bv  = (const float*)d_in[8];
    const float* Wf  = (const float*)d_in[9];
    const float* bfb = (const float*)d_in[10];
    float* ws = (float*)d_ws;
    float* o  = (float*)d_out;

    hipLaunchKernelGGL(k0_pre,  dim3(291),  dim3(256), 0, stream,
                       Wq, bq, Wk, bk, Wv, bv, Wf, bfb, ws);
    hipLaunchKernelGGL(k1_proj, dim3(1000), dim3(256), 0, stream, queries, E, ws);
    hipLaunchKernelGGL(k2_attn, dim3(6400), dim3(128), 0, stream, keys, E, ws);
    hipLaunchKernelGGL(k3_out,  dim3(800),  dim3(256), 0, stream, ws, o);
}